// Round 3
// baseline (64.662 us; speedup 1.0000x reference)
//
#include <hip/hip_runtime.h>

// 1-node pipeline (was 2): fused {compact-into-LDS + dense PxQ pair sum +
// device-side gather/finalize in block 0}. No cooperative launch (round-1
// coop kernel killed the container). Gather is structurally deadlock-free:
// writer blocks never wait; only block 0 polls, and every slot it polls is
// written unconditionally. Payload (float partial) is packed INSIDE the
// 64-bit atomic (hi=MAGIC, lo=float bits) -> no fence/ordering needed.
#define GRID  256          // 1 block/CU
#define PBLK  512          // 8 waves
#define EPT   16           // compaction elements/thread: 512*16 = 8192 = N
#define RT    9            // pos per thread per chunk: 512*9 = 4608 >= P (11 sigma)
#define NMAX  8192
#define MAGIC 0x5AC0FFEEu

#define LOG2E 1.4426950408889634f
#define LN2   0.6931471805599453
#define BIGF  1.0e30f      // mask bias: x=-1e30 -> max term 0, exp2(-|x|)=0

__device__ __forceinline__ float fast_exp2(float x) {
#if __has_builtin(__builtin_amdgcn_exp2f)
    return __builtin_amdgcn_exp2f(x);      // v_exp_f32
#else
    return exp2f(x);
#endif
}
__device__ __forceinline__ float fast_log2(float x) {
#if __has_builtin(__builtin_amdgcn_logf)
    return __builtin_amdgcn_logf(x);       // v_log_f32
#else
    return log2f(x);
#endif
}

__global__ __launch_bounds__(PBLK) void fused_kernel(
        const float* __restrict__ v,
        const int*   __restrict__ ty,
        unsigned long long* __restrict__ slots,   // ws: GRID x u64 (poisoned each iter)
        float*       __restrict__ out,
        int N) {
    // pos values grow from buf[0], neg values grow down from buf[N-1]:
    // exactly N slots since every element is pos or neg (ty in {0,1}).
    __shared__ float buf[NMAX];
    __shared__ int   wtot[PBLK / 64];
    __shared__ float wsum[PBLK / 64];
    __shared__ float gat[GRID];

    const int tid  = threadIdx.x;
    const int lane = tid & 63;
    const int wid  = tid >> 6;
    const int e0   = tid * EPT;              // my 16 consecutive elements

    // ---- Phase A: per-thread positive bitmask over [e0, e0+EPT) ----
    int pmask = 0;
    if (e0 + EPT <= N) {
        #pragma unroll
        for (int j = 0; j < EPT / 4; ++j) {
            const int4 t4 = *reinterpret_cast<const int4*>(ty + e0 + 4 * j);
            pmask |= (t4.x == 1) << (4 * j + 0);
            pmask |= (t4.y == 1) << (4 * j + 1);
            pmask |= (t4.z == 1) << (4 * j + 2);
            pmask |= (t4.w == 1) << (4 * j + 3);
        }
    } else {
        for (int k = 0; k < EPT; ++k) {
            const int i = e0 + k;
            if (i < N && ty[i] == 1) pmask |= 1 << k;
        }
    }
    const int cp = __popc(pmask);

    // ---- Phase B: deterministic exclusive prefix (global-index order) ----
    int scan = cp;                           // wave inclusive scan
    #pragma unroll
    for (int off = 1; off < 64; off <<= 1) {
        const int nb = __shfl_up(scan, off, 64);
        if (lane >= off) scan += nb;
    }
    if (lane == 63) wtot[wid] = scan;
    __syncthreads();

    int waveBase = 0, P = 0;
    #pragma unroll
    for (int w = 0; w < PBLK / 64; ++w) {
        const int t = wtot[w];
        if (w < wid) waveBase += t;
        P += t;
    }
    const int elemsBefore = (e0 < N) ? e0 : N;
    int pP = waveBase + scan - cp;           // exclusive positive base
    int pN = elemsBefore - pP;               // exclusive negative base
    const int Q = N - P;

    // ---- Phase C: scatter pred*log2(e) into compacted LDS lists ----
    if (e0 + EPT <= N) {
        #pragma unroll
        for (int j = 0; j < EPT / 4; ++j) {
            const float4 f4 = *reinterpret_cast<const float4*>(v + e0 + 4 * j);
            const float vals[4] = {f4.x, f4.y, f4.z, f4.w};
            #pragma unroll
            for (int e = 0; e < 4; ++e) {
                const float val = vals[e] * LOG2E;
                if (pmask & (1 << (4 * j + e))) buf[pP++] = val;
                else                            buf[N - 1 - (pN++)] = val;
            }
        }
    } else {
        for (int k = 0; k < EPT; ++k) {
            const int i = e0 + k;
            if (i < N) {
                const float val = v[i] * LOG2E;
                if (pmask & (1 << k)) buf[pP++] = val;
                else                  buf[N - 1 - (pN++)] = val;
            }
        }
    }
    __syncthreads();

    // ---- Pair phase: identical math to the proven pair_kernel, LDS-fed ----
    // Per r-iter: sub, max, add, exp2(-|x|, mods fold), fmac; one v_log per
    // column (product of 9 factors <= 2^9, no overflow). No divergence.
    float accm = 0.0f;   // sum of max(x,0) terms
    float accl = 0.0f;   // sum of log2(prod) terms
    for (int base = 0; base < P; base += RT * PBLK) {   // 1 chunk for P<=4608
        float pa[RT];
        #pragma unroll
        for (int r = 0; r < RT; ++r) {
            const int idx = base + r * PBLK + tid;      // lane-consecutive
            pa[r] = (idx < P) ? buf[idx] : BIGF;
        }
        for (int b = blockIdx.x; b < Q; b += GRID) {
            const float vbl = buf[N - 1 - b];           // uniform LDS broadcast
            float p = 1.0f;
            #pragma unroll
            for (int r = 0; r < RT; ++r) {
                const float x = vbl - pa[r];
                accm += fmaxf(x, 0.0f);
                const float e = fast_exp2(-fabsf(x));   // src mods fold
                p = fmaf(p, e, p);                      // p *= (1 + e)
            }
            accl += fast_log2(p);                       // 1 trans per 9 pairs
        }
    }

    // ---- Block reduce, publish partial packed inside one 64-bit atomic ----
    float acc = accm + accl;
    #pragma unroll
    for (int off = 32; off > 0; off >>= 1)
        acc += __shfl_down(acc, off, 64);
    if (lane == 0) wsum[wid] = acc;
    __syncthreads();
    if (tid == 0) {
        float s = 0.0f;
        #pragma unroll
        for (int w = 0; w < PBLK / 64; ++w) s += wsum[w];
        const unsigned long long val =
            ((unsigned long long)MAGIC << 32) |
            (unsigned long long)__float_as_uint(s);
        atomicExch(&slots[blockIdx.x], val);   // device-scope, payload inside
    }

    // ---- Block 0: gather all partials, deterministic double reduce ----
    if (blockIdx.x == 0) {
        if (tid < GRID) {
            unsigned long long vv;
            int guard = 0;
            for (;;) {
                vv = atomicAdd(&slots[tid], 0ull);   // coherent-point RMW read
                if ((unsigned int)(vv >> 32) == MAGIC) break;
                if (++guard > (1 << 26)) break;      // hang-proof bound
                __builtin_amdgcn_s_sleep(2);
            }
            gat[tid] = __uint_as_float((unsigned int)vv);
        }
        __syncthreads();
        if (tid == 0) {
            double sd = 0.0;
            for (int b = 0; b < GRID; ++b) sd += (double)gat[b];  // fixed order
            const double Pd = (double)P;
            out[0] = (float)(sd * LN2 / (Pd * ((double)N - Pd)));
        }
    }
}

extern "C" void kernel_launch(void* const* d_in, const int* in_sizes, int n_in,
                              void* d_out, int out_size, void* d_ws, size_t ws_size,
                              hipStream_t stream) {
    const float* v  = (const float*)d_in[0];   // pred_y fp32, N = n*K = 8192
    const int*   ty = (const int*)d_in[1];     // true_y int32 {0,1}
    float* out = (float*)d_out;
    const int N = in_sizes[0];

    unsigned long long* slots = (unsigned long long*)d_ws;  // GRID x u64

    fused_kernel<<<GRID, PBLK, 0, stream>>>(v, ty, slots, out, N);
}

// Round 4
// 62.249 us; speedup vs baseline: 1.0388x; 1.0388x over previous
//
#include <hip/hip_runtime.h>

// 2-node pipeline (round-2 structure, proven 63.3 us — round-3's 1-node
// device gather regressed to 64.7 and is abandoned). Change this round:
// GRID 256 -> 512 (2 blocks/CU, 4 waves/SIMD instead of 2) to halve the
// pair-phase critical path and hide exp2/log2 transcendental latency.
#define GRID  512          // 2 blocks/CU
#define PBLK  512          // 8 waves
#define EPT   16           // compaction elements/thread: 512*16 = 8192 = N
#define RT    9            // pos per thread per chunk: 512*9 = 4608 >= P (11 sigma)
#define NMAX  8192

#define LOG2E 1.4426950408889634f
#define LN2   0.6931471805599453
#define BIGF  1.0e30f      // mask bias: x=-1e30 -> max term 0, exp2(-|x|)=0

__device__ __forceinline__ float fast_exp2(float x) {
#if __has_builtin(__builtin_amdgcn_exp2f)
    return __builtin_amdgcn_exp2f(x);      // v_exp_f32
#else
    return exp2f(x);
#endif
}
__device__ __forceinline__ float fast_log2(float x) {
#if __has_builtin(__builtin_amdgcn_logf)
    return __builtin_amdgcn_logf(x);       // v_log_f32
#else
    return log2f(x);
#endif
}

__global__ __launch_bounds__(PBLK, 4) void fused_kernel(
        const float* __restrict__ v,
        const int*   __restrict__ ty,
        int*         __restrict__ pcount,     // ws[0]: P (block 0 writes)
        float*       __restrict__ partials,   // ws+64: float[GRID]
        int N) {
    // pos values grow from buf[0], neg values grow down from buf[N-1]:
    // exactly N slots since every element is pos or neg (ty in {0,1}).
    __shared__ float buf[NMAX];
    __shared__ int   wtot[PBLK / 64];
    __shared__ float wsum[PBLK / 64];

    const int tid  = threadIdx.x;
    const int lane = tid & 63;
    const int wid  = tid >> 6;
    const int e0   = tid * EPT;              // my 16 consecutive elements

    // ---- Phase A: per-thread positive bitmask over [e0, e0+EPT) ----
    int pmask = 0;
    if (e0 + EPT <= N) {
        #pragma unroll
        for (int j = 0; j < EPT / 4; ++j) {
            const int4 t4 = *reinterpret_cast<const int4*>(ty + e0 + 4 * j);
            pmask |= (t4.x == 1) << (4 * j + 0);
            pmask |= (t4.y == 1) << (4 * j + 1);
            pmask |= (t4.z == 1) << (4 * j + 2);
            pmask |= (t4.w == 1) << (4 * j + 3);
        }
    } else {
        for (int k = 0; k < EPT; ++k) {
            const int i = e0 + k;
            if (i < N && ty[i] == 1) pmask |= 1 << k;
        }
    }
    const int cp = __popc(pmask);

    // ---- Phase B: deterministic exclusive prefix (global-index order) ----
    int scan = cp;                           // wave inclusive scan
    #pragma unroll
    for (int off = 1; off < 64; off <<= 1) {
        const int nb = __shfl_up(scan, off, 64);
        if (lane >= off) scan += nb;
    }
    if (lane == 63) wtot[wid] = scan;
    __syncthreads();

    int waveBase = 0, P = 0;
    #pragma unroll
    for (int w = 0; w < PBLK / 64; ++w) {
        const int t = wtot[w];
        if (w < wid) waveBase += t;
        P += t;
    }
    const int elemsBefore = (e0 < N) ? e0 : N;
    int pP = waveBase + scan - cp;           // exclusive positive base
    int pN = elemsBefore - pP;               // exclusive negative base
    const int Q = N - P;

    // ---- Phase C: scatter pred*log2(e) into compacted LDS lists ----
    if (e0 + EPT <= N) {
        #pragma unroll
        for (int j = 0; j < EPT / 4; ++j) {
            const float4 f4 = *reinterpret_cast<const float4*>(v + e0 + 4 * j);
            const float vals[4] = {f4.x, f4.y, f4.z, f4.w};
            #pragma unroll
            for (int e = 0; e < 4; ++e) {
                const float val = vals[e] * LOG2E;
                if (pmask & (1 << (4 * j + e))) buf[pP++] = val;
                else                            buf[N - 1 - (pN++)] = val;
            }
        }
    } else {
        for (int k = 0; k < EPT; ++k) {
            const int i = e0 + k;
            if (i < N) {
                const float val = v[i] * LOG2E;
                if (pmask & (1 << k)) buf[pP++] = val;
                else                  buf[N - 1 - (pN++)] = val;
            }
        }
    }
    __syncthreads();

    // ---- Pair phase: identical math to the proven pair_kernel, LDS-fed ----
    // Per r-iter: sub, max, add, exp2(-|x|, mods fold), fmac; one v_log per
    // column (product of 9 factors <= 2^9, no overflow). No divergence.
    float accm = 0.0f;   // sum of max(x,0) terms
    float accl = 0.0f;   // sum of log2(prod) terms
    for (int base = 0; base < P; base += RT * PBLK) {   // 1 chunk for P<=4608
        float pa[RT];
        #pragma unroll
        for (int r = 0; r < RT; ++r) {
            const int idx = base + r * PBLK + tid;      // lane-consecutive
            pa[r] = (idx < P) ? buf[idx] : BIGF;
        }
        for (int b = blockIdx.x; b < Q; b += GRID) {
            const float vbl = buf[N - 1 - b];           // uniform LDS broadcast
            float p = 1.0f;
            #pragma unroll
            for (int r = 0; r < RT; ++r) {
                const float x = vbl - pa[r];
                accm += fmaxf(x, 0.0f);
                const float e = fast_exp2(-fabsf(x));   // src mods fold
                p = fmaf(p, e, p);                      // p *= (1 + e)
            }
            accl += fast_log2(p);                       // 1 trans per 9 pairs
        }
    }

    // ---- Block reduce -> partials[bid] (unconditional, deterministic) ----
    float acc = accm + accl;
    #pragma unroll
    for (int off = 32; off > 0; off >>= 1)
        acc += __shfl_down(acc, off, 64);
    if (lane == 0) wsum[wid] = acc;
    __syncthreads();
    if (tid == 0) {
        float s = 0.0f;
        #pragma unroll
        for (int w = 0; w < PBLK / 64; ++w) s += wsum[w];
        partials[blockIdx.x] = s;
        if (blockIdx.x == 0) pcount[0] = P;
    }
}

// out = ln2 * sum(partials) / (P*(N-P)), double accumulation, fixed order.
__global__ __launch_bounds__(GRID) void finalize_kernel(
        const float* __restrict__ partials,
        const int*   __restrict__ pcount,
        float*       __restrict__ out,
        int N) {
    const int tid = threadIdx.x;
    __shared__ double sd[GRID];
    sd[tid] = (double)partials[tid];         // nparts == GRID == blockDim.x
    __syncthreads();
    for (int off = GRID / 2; off > 0; off >>= 1) {
        if (tid < off) sd[tid] += sd[tid + off];
        __syncthreads();
    }
    if (tid == 0) {
        const double P = (double)pcount[0];
        const double denom = P * ((double)N - P);
        out[0] = (float)(sd[0] * LN2 / denom);
    }
}

extern "C" void kernel_launch(void* const* d_in, const int* in_sizes, int n_in,
                              void* d_out, int out_size, void* d_ws, size_t ws_size,
                              hipStream_t stream) {
    const float* v  = (const float*)d_in[0];   // pred_y fp32, N = n*K = 8192
    const int*   ty = (const int*)d_in[1];     // true_y int32 {0,1}
    float* out = (float*)d_out;
    const int N = in_sizes[0];

    // ws layout: [pcount: int][pad to 64B][partials: GRID floats]
    char*  ws       = (char*)d_ws;
    int*   pcount   = (int*)ws;
    float* partials = (float*)(ws + 64);

    fused_kernel<<<GRID, PBLK, 0, stream>>>(v, ty, pcount, partials, N);
    finalize_kernel<<<1, GRID, 0, stream>>>(partials, pcount, out, N);
}